// Round 1
// baseline (129.937 us; speedup 1.0000x reference)
//
#include <hip/hip_runtime.h>

#define TILE   2048
#define NLOAD  (TILE + 32)          // 2080 floats staged (tile + 31 halo, rounded to float4)
#define WIDTH  262144
#define OUTW   (WIDTH - 31)         // 262113 valid outputs per row
#define SCALE_V 0.17782794100389229f // sqrt(10^(-15/10))

__global__ __launch_bounds__(256) void fused_hammer(
    const float* __restrict__ xr_g,   const float* __restrict__ xi_g,
    const float* __restrict__ w1_pre, const float* __restrict__ w2_pre,
    const float* __restrict__ wfr,    const float* __restrict__ wfi,
    const float* __restrict__ w1_post,const float* __restrict__ b1_post,
    const float* __restrict__ w2_post,const float* __restrict__ b2_post,
    float* __restrict__ out)
{
    __shared__ __align__(16) float s_r[NLOAD];
    __shared__ __align__(16) float s_i[NLOAD];

    const int tid    = threadIdx.x;
    const int tstart = blockIdx.x * TILE;   // output offset of this tile within the row
    const int brow   = blockIdx.y;          // batch row 0..15
    const long rowbase = (long)brow * WIDTH;

    // ---- uniform (scalar) weight prep for pre-MLP ----
    // tanh(x) = 1 - 2/(exp(2x)+1);  m = sum(w2) - 2*sum(w2 / (exp(2*mag*w1)+1))
    float w1v[8], w2v[8];
    float sumw2 = 0.f;
#pragma unroll
    for (int f = 0; f < 8; ++f) {
        w1v[f] = 2.0f * w1_pre[f];
        w2v[f] = w2_pre[f];
        sumw2 += w2_pre[f];
    }

    // ---- stage xh_r / xh_i into LDS (tile + halo) ----
    for (int p = tid; p < NLOAD / 4; p += 256) {
        const int g = tstart + 4 * p;       // float index within the row
        float4 vr, vi;
        if (g + 3 < WIDTH) {
            vr = *(const float4*)(xr_g + rowbase + g);
            vi = *(const float4*)(xi_g + rowbase + g);
        } else {                             // only the last tile of a row
            float rr[4], ii[4];
#pragma unroll
            for (int e = 0; e < 4; ++e) {
                const int gg = g + e;
                rr[e] = (gg < WIDTH) ? xr_g[rowbase + gg] : 0.f;
                ii[e] = (gg < WIDTH) ? xi_g[rowbase + gg] : 0.f;
            }
            vr = make_float4(rr[0], rr[1], rr[2], rr[3]);
            vi = make_float4(ii[0], ii[1], ii[2], ii[3]);
        }
        float hr[4], hi[4];
        const float* vrf = &vr.x;
        const float* vif = &vi.x;
#pragma unroll
        for (int e = 0; e < 4; ++e) {
            const float r  = vrf[e], im = vif[e];
            const float sq = fmaf(r, r, im * im);
            const float rs = (sq > 0.f) ? __builtin_amdgcn_rsqf(sq) : 0.f; // rs = 1/mag
            const float mag = sq * rs;                                      // sqrt(sq)
            float tw = 0.f;
#pragma unroll
            for (int f = 0; f < 8; ++f) {
                const float e2 = __expf(mag * w1v[f]);           // exp(2*mag*w1[f])
                const float tt = __builtin_amdgcn_rcpf(e2 + 1.0f);
                tw = fmaf(w2v[f], tt, tw);
            }
            const float m = sumw2 - 2.0f * tw;   // m = sum_f w2[f]*tanh(mag*w1[f])
            const float s = m * rs;              // m / mag  (cos,sin) = (r,i)*rs
            hr[e] = s * r;
            hi[e] = s * im;
        }
        *(float4*)&s_r[4 * p] = make_float4(hr[0], hr[1], hr[2], hr[3]);
        *(float4*)&s_i[4 * p] = make_float4(hi[0], hi[1], hi[2], hi[3]);
    }
    __syncthreads();

    // ---- length-32 complex FIR: 8 consecutive outputs per thread ----
    const int base = tid * 8;                 // output offset within tile
    float accr[8], acci[8];
#pragma unroll
    for (int j = 0; j < 8; ++j) { accr[j] = 0.f; acci[j] = 0.f; }

#pragma unroll
    for (int tc = 0; tc < 4; ++tc) {          // 4 chunks of 8 taps
        float wrf[16], wif[16];               // window [base+8tc, base+8tc+16)
        const int wb = base + 8 * tc;         // 32B-aligned (base = 8*tid)
#pragma unroll
        for (int q = 0; q < 4; ++q) {
            *(float4*)&wrf[4 * q] = *(const float4*)&s_r[wb + 4 * q];
            *(float4*)&wif[4 * q] = *(const float4*)&s_i[wb + 4 * q];
        }
#pragma unroll
        for (int tt = 0; tt < 8; ++tt) {
            const float fr = wfr[8 * tc + tt];   // uniform -> s_load
            const float fi = wfi[8 * tc + tt];
#pragma unroll
            for (int j = 0; j < 8; ++j) {
                const float ar = wrf[j + tt];
                const float ai = wif[j + tt];
                accr[j] = fmaf(fr,  ar, accr[j]);
                accr[j] = fmaf(-fi, ai, accr[j]);
                acci[j] = fmaf(fr,  ai, acci[j]);
                acci[j] = fmaf(fi,  ar, acci[j]);
            }
        }
    }

    // ---- post MLP (1->8 relu ->1) + polar reconstruct + store ----
    float w1p[8], b1p[8], w2p[8];
#pragma unroll
    for (int f = 0; f < 8; ++f) { w1p[f] = w1_post[f]; b1p[f] = b1_post[f]; w2p[f] = w2_post[f]; }
    const float b2p = b2_post[0];

#pragma unroll
    for (int j = 0; j < 8; ++j) {
        const int o = tstart + base + j;
        if (o < OUTW) {
            const float zr  = accr[j], zi = acci[j];
            const float zsq = fmaf(zr, zr, zi * zi);
            const float rs  = (zsq > 0.f) ? __builtin_amdgcn_rsqf(zsq) : 0.f; // 1/|z|
            const float zmag = zsq * rs;
            float zm = b2p;
#pragma unroll
            for (int f = 0; f < 8; ++f) {
                const float gfv = fmaf(zmag, w1p[f], b1p[f]);
                zm = fmaf(fmaxf(gfv, 0.f), w2p[f], zm);
            }
            const float t = SCALE_V * zm * rs;
            float2 o2;
            o2.x = (zsq > 0.f) ? t * zr : SCALE_V * zm;  // zmag==0 -> phase 0 -> (cos,sin)=(1,0)
            o2.y = t * zi;
            *(float2*)&out[((long)brow * OUTW + o) * 2] = o2;
        }
    }
}

extern "C" void kernel_launch(void* const* d_in, const int* in_sizes, int n_in,
                              void* d_out, int out_size, void* d_ws, size_t ws_size,
                              hipStream_t stream) {
    const int blocks_w = (OUTW + TILE - 1) / TILE;   // 128
    dim3 grid(blocks_w, 16);
    fused_hammer<<<grid, 256, 0, stream>>>(
        (const float*)d_in[0], (const float*)d_in[1],
        (const float*)d_in[2], (const float*)d_in[3],
        (const float*)d_in[4], (const float*)d_in[5],
        (const float*)d_in[6], (const float*)d_in[7],
        (const float*)d_in[8], (const float*)d_in[9],
        (float*)d_out);
}

// Round 2
// 123.512 us; speedup vs baseline: 1.0520x; 1.0520x over previous
//
#include <hip/hip_runtime.h>

#define TILE   2048
#define NLOAD  (TILE + 32)          // 2080 floats staged (tile + 31 halo, rounded to float4)
#define NBLK   (NLOAD / 4)          // 520 16-byte blocks
#define WIDTH  262144
#define OUTW   (WIDTH - 31)         // 262113 valid outputs per row
#define SCALE_V 0.17782794100389229f // sqrt(10^(-15/10))
#define LOG2E_X2 2.8853900817779268f // 2*log2(e)

// XOR swizzle at 16B-block granularity: kills the 16-way bank conflict of
// stride-8-float window reads (B = 2*tid + c -> bank group (B&7)^((B>>3)&7)
// covers all 8 groups once per 8 lanes). Bijective within each 8-block group,
// so physical index stays < NBLK (520 = 65*8).
__device__ __forceinline__ int swz(int b) { return b ^ ((b >> 3) & 7); }

__global__ __launch_bounds__(256) void fused_hammer(
    const float* __restrict__ xr_g,   const float* __restrict__ xi_g,
    const float* __restrict__ w1_pre, const float* __restrict__ w2_pre,
    const float* __restrict__ wfr,    const float* __restrict__ wfi,
    const float* __restrict__ w1_post,const float* __restrict__ b1_post,
    const float* __restrict__ w2_post,const float* __restrict__ b2_post,
    float* __restrict__ out)
{
    __shared__ __align__(16) float s_r[NLOAD];
    __shared__ __align__(16) float s_i[NLOAD];

    const int tid    = threadIdx.x;
    const int tstart = blockIdx.x * TILE;   // output offset of this tile within the row
    const int brow   = blockIdx.y;          // batch row 0..15
    const long rowbase = (long)brow * WIDTH;

    // ---- uniform (scalar) weight prep for pre-MLP ----
    // tanh(x) = 1 - 2/(exp(2x)+1);  m = sum(w2) - 2*sum(w2 / (exp2(mag*w1*2log2e)+1))
    float w1v[8], w2v[8];
    float sumw2 = 0.f;
#pragma unroll
    for (int f = 0; f < 8; ++f) {
        w1v[f] = LOG2E_X2 * w1_pre[f];      // feeds v_exp_f32 directly
        w2v[f] = w2_pre[f];
        sumw2 += w2_pre[f];
    }

    // ---- stage xh_r / xh_i into LDS (tile + halo), swizzled ----
    for (int p = tid; p < NBLK; p += 256) {
        const int g = tstart + 4 * p;       // float index within the row
        float4 vr, vi;
        if (g + 3 < WIDTH) {
            vr = *(const float4*)(xr_g + rowbase + g);
            vi = *(const float4*)(xi_g + rowbase + g);
        } else {                             // only the last tile of a row
            float rr[4], ii[4];
#pragma unroll
            for (int e = 0; e < 4; ++e) {
                const int gg = g + e;
                rr[e] = (gg < WIDTH) ? xr_g[rowbase + gg] : 0.f;
                ii[e] = (gg < WIDTH) ? xi_g[rowbase + gg] : 0.f;
            }
            vr = make_float4(rr[0], rr[1], rr[2], rr[3]);
            vi = make_float4(ii[0], ii[1], ii[2], ii[3]);
        }
        float hr[4], hi[4];
        const float* vrf = &vr.x;
        const float* vif = &vi.x;
#pragma unroll
        for (int e = 0; e < 4; ++e) {
            const float r  = vrf[e], im = vif[e];
            const float sq = fmaf(r, r, im * im);
            const float rs = (sq > 0.f) ? __builtin_amdgcn_rsqf(sq) : 0.f; // rs = 1/mag
            const float mag = sq * rs;                                      // sqrt(sq)
            float tw = 0.f;
#pragma unroll
            for (int f = 0; f < 8; ++f) {
                const float e2 = __builtin_amdgcn_exp2f(mag * w1v[f]);  // exp(2*mag*w1[f])
                const float tt = __builtin_amdgcn_rcpf(e2 + 1.0f);
                tw = fmaf(w2v[f], tt, tw);
            }
            const float m = sumw2 - 2.0f * tw;   // m = sum_f w2[f]*tanh(mag*w1[f])
            const float s = m * rs;              // m / mag  (cos,sin) = (r,i)*rs
            hr[e] = s * r;
            hi[e] = s * im;
        }
        const int ph = 4 * swz(p);
        *(float4*)&s_r[ph] = make_float4(hr[0], hr[1], hr[2], hr[3]);
        *(float4*)&s_i[ph] = make_float4(hi[0], hi[1], hi[2], hi[3]);
    }
    __syncthreads();

    // ---- length-32 complex FIR: 8 consecutive outputs per thread ----
    const int base = tid * 8;                 // output offset within tile
    float accr[8], acci[8];
#pragma unroll
    for (int j = 0; j < 8; ++j) { accr[j] = 0.f; acci[j] = 0.f; }

#pragma unroll
    for (int tc = 0; tc < 4; ++tc) {          // 4 chunks of 8 taps
        float wrf[16], wif[16];               // window [base+8tc, base+8tc+16)
#pragma unroll
        for (int q = 0; q < 4; ++q) {
            const int B  = 2 * tid + 2 * tc + q;  // logical 16B block
            const int ph = 4 * swz(B);
            *(float4*)&wrf[4 * q] = *(const float4*)&s_r[ph];
            *(float4*)&wif[4 * q] = *(const float4*)&s_i[ph];
        }
#pragma unroll
        for (int tt = 0; tt < 8; ++tt) {
            const float fr = wfr[8 * tc + tt];   // uniform -> s_load
            const float fi = wfi[8 * tc + tt];
#pragma unroll
            for (int j = 0; j < 8; ++j) {
                const float ar = wrf[j + tt];
                const float ai = wif[j + tt];
                accr[j] = fmaf(fr,  ar, accr[j]);
                accr[j] = fmaf(-fi, ai, accr[j]);
                acci[j] = fmaf(fr,  ai, acci[j]);
                acci[j] = fmaf(fi,  ar, acci[j]);
            }
        }
    }

    // ---- post MLP (1->8 relu ->1) + polar reconstruct + store ----
    float w1p[8], b1p[8], w2p[8];
#pragma unroll
    for (int f = 0; f < 8; ++f) { w1p[f] = w1_post[f]; b1p[f] = b1_post[f]; w2p[f] = w2_post[f]; }
    const float b2p = b2_post[0];

#pragma unroll
    for (int j = 0; j < 8; ++j) {
        const int o = tstart + base + j;
        if (o < OUTW) {
            const float zr  = accr[j], zi = acci[j];
            const float zsq = fmaf(zr, zr, zi * zi);
            const float rs  = (zsq > 0.f) ? __builtin_amdgcn_rsqf(zsq) : 0.f; // 1/|z|
            const float zmag = zsq * rs;
            float zm = b2p;
#pragma unroll
            for (int f = 0; f < 8; ++f) {
                const float gfv = fmaf(zmag, w1p[f], b1p[f]);
                zm = fmaf(fmaxf(gfv, 0.f), w2p[f], zm);
            }
            const float t = SCALE_V * zm * rs;
            float2 o2;
            o2.x = (zsq > 0.f) ? t * zr : SCALE_V * zm;  // zmag==0 -> phase 0 -> (cos,sin)=(1,0)
            o2.y = t * zi;
            *(float2*)&out[((long)brow * OUTW + o) * 2] = o2;
        }
    }
}

extern "C" void kernel_launch(void* const* d_in, const int* in_sizes, int n_in,
                              void* d_out, int out_size, void* d_ws, size_t ws_size,
                              hipStream_t stream) {
    const int blocks_w = (OUTW + TILE - 1) / TILE;   // 128
    dim3 grid(blocks_w, 16);
    fused_hammer<<<grid, 256, 0, stream>>>(
        (const float*)d_in[0], (const float*)d_in[1],
        (const float*)d_in[2], (const float*)d_in[3],
        (const float*)d_in[4], (const float*)d_in[5],
        (const float*)d_in[6], (const float*)d_in[7],
        (const float*)d_in[8], (const float*)d_in[9],
        (float*)d_out);
}

// Round 3
// 113.903 us; speedup vs baseline: 1.1408x; 1.0844x over previous
//
#include <hip/hip_runtime.h>

#define TILE   2048
#define NS     2096                 // staged elements per block (TILE + 48)
#define WIDTH  262144
#define OUTW   (WIDTH - 31)         // 262113
#define SCALE_V 0.17782794100389229f // sqrt(10^(-15/10))
#define LOG2E_X2 2.8853900817779268f // 2*log2(e)

typedef _Float16 half8  __attribute__((ext_vector_type(8)));
typedef _Float16 half4v __attribute__((ext_vector_type(4)));
typedef float    floatx4 __attribute__((ext_vector_type(4)));

__device__ __forceinline__ float wload(const float* __restrict__ w, int t) {
    return (t >= 0 && t < 32) ? w[t] : 0.0f;
}

#define MFMA16(A, B, C) __builtin_amdgcn_mfma_f32_16x16x32_f16((A), (B), (C), 0, 0, 0)

// FIR as Toeplitz MFMA:
//   y[bo+16n+j] = sum_t w[t] x[bo+16n+j+t],  j=0..15 (D rows), n=0..15 (D cols)
//   chunk1: k=0..31: A1[j][k]=w[k-j] (k>=j), B1[k][n]=x[bo+16n+k]
//   chunk2: k=0..15: taps 17..31 via A2[j][k]=w[k+32-j] (j>=k+1), B2=x[bo+16n+32+k]
//   complex: zr = wr*xr - wi*xi, zi = wr*xi + wi*xr; chunk2 for both components
//   packed into ONE mixed-B MFMA (k<16 from xr, k>=16 from xi).
//   precision: x and w split into f16 hi+lo; terms wh*xh + wh*xl + wl*xh.

__global__ __launch_bounds__(256) void fused_hammer_mfma(
    const float* __restrict__ xr_g,   const float* __restrict__ xi_g,
    const float* __restrict__ w1_pre, const float* __restrict__ w2_pre,
    const float* __restrict__ wfr,    const float* __restrict__ wfi,
    const float* __restrict__ w1_post,const float* __restrict__ b1_post,
    const float* __restrict__ w2_post,const float* __restrict__ b2_post,
    float* __restrict__ out)
{
    __shared__ __align__(16) _Float16 s_rh[NS];
    __shared__ __align__(16) _Float16 s_rl[NS];
    __shared__ __align__(16) _Float16 s_ih[NS];
    __shared__ __align__(16) _Float16 s_il[NS];

    const int tid    = threadIdx.x;
    const int lane   = tid & 63;
    const int wv     = tid >> 6;
    const int tstart = blockIdx.x * TILE;
    const int brow   = blockIdx.y;
    const long rowbase = (long)brow * WIDTH;

    // ---- pre-MLP uniform weights ----
    float w1v[8], w2v[8], sumw2 = 0.f;
#pragma unroll
    for (int f = 0; f < 8; ++f) {
        w1v[f] = LOG2E_X2 * w1_pre[f];
        w2v[f] = w2_pre[f];
        sumw2 += w2_pre[f];
    }
    // ---- post-MLP uniform weights ----
    float w1p[8], b1p[8], w2p[8];
#pragma unroll
    for (int f = 0; f < 8; ++f) { w1p[f] = w1_post[f]; b1p[f] = b1_post[f]; w2p[f] = w2_post[f]; }
    const float b2p = b2_post[0];

    // ---- build Toeplitz weight fragments (hi/lo f16), once per lane ----
    const int jA = lane & 15;    // A row m / D col n share lane&15; D row uses lane>>4
    const int kg = lane >> 4;
    half8 A1r_h, A1r_l, A1mi_h, A1mi_l, A1i_h, A1i_l, A2r_h, A2r_l, A2i_h, A2i_l;
#pragma unroll
    for (int jj = 0; jj < 8; ++jj) {
        const int k  = 8 * kg + jj;
        const int t1 = k - jA;
        const float wr1 = wload(wfr, t1);
        const float wi1 = wload(wfi, t1);
        const int t2 = (k < 16) ? (k + 32 - jA) : (k + 16 - jA);
        const float wr2 = wload(wfr, t2);
        const float wi2 = wload(wfi, t2);
        const float a2r = (k < 16) ? wr2 : -wi2;   // zr second chunk: [wr | -wi]
        const float a2i = (k < 16) ? wi2 : wr2;    // zi second chunk: [wi |  wr]
        _Float16 h;
        h = (_Float16)wr1;   A1r_h[jj]  = h; A1r_l[jj]  = (_Float16)(wr1 - (float)h);
        h = (_Float16)(-wi1);A1mi_h[jj] = h; A1mi_l[jj] = (_Float16)(-wi1 - (float)h);
        h = (_Float16)wi1;   A1i_h[jj]  = h; A1i_l[jj]  = (_Float16)(wi1 - (float)h);
        h = (_Float16)a2r;   A2r_h[jj]  = h; A2r_l[jj]  = (_Float16)(a2r - (float)h);
        h = (_Float16)a2i;   A2i_h[jj]  = h; A2i_l[jj]  = (_Float16)(a2i - (float)h);
    }

    // ---- stage pre-MLP output into LDS as f16 hi/lo ----
    for (int p = tid; p < NS / 4; p += 256) {
        const int g = tstart + 4 * p;
        float4 vr, vi;
        if (g + 3 < WIDTH) {
            vr = *(const float4*)(xr_g + rowbase + g);
            vi = *(const float4*)(xi_g + rowbase + g);
        } else {
            float rr[4], ii[4];
#pragma unroll
            for (int e = 0; e < 4; ++e) {
                const int gg = g + e;
                rr[e] = (gg < WIDTH) ? xr_g[rowbase + gg] : 0.f;
                ii[e] = (gg < WIDTH) ? xi_g[rowbase + gg] : 0.f;
            }
            vr = make_float4(rr[0], rr[1], rr[2], rr[3]);
            vi = make_float4(ii[0], ii[1], ii[2], ii[3]);
        }
        const float* vrf = &vr.x;
        const float* vif = &vi.x;
        half4v rh, rl, ih, il;
#pragma unroll
        for (int e = 0; e < 4; ++e) {
            const float r  = vrf[e], im = vif[e];
            const float sq = fmaf(r, r, im * im);
            const float rs = (sq > 0.f) ? __builtin_amdgcn_rsqf(sq) : 0.f; // 1/mag
            const float mag = sq * rs;
            float tw = 0.f;
#pragma unroll
            for (int f = 0; f < 8; ++f) {
                const float e2 = __builtin_amdgcn_exp2f(mag * w1v[f]);
                tw = fmaf(w2v[f], __builtin_amdgcn_rcpf(e2 + 1.0f), tw);
            }
            const float m = sumw2 - 2.0f * tw;
            const float s = m * rs;
            const float xhr = s * r;
            const float xhi = s * im;
            const _Float16 hr = (_Float16)xhr;
            const _Float16 hi = (_Float16)xhi;
            rh[e] = hr; rl[e] = (_Float16)(xhr - (float)hr);
            ih[e] = hi; il[e] = (_Float16)(xhi - (float)hi);
        }
        *(half4v*)&s_rh[4 * p] = rh;
        *(half4v*)&s_rl[4 * p] = rl;
        *(half4v*)&s_ih[4 * p] = ih;
        *(half4v*)&s_il[4 * p] = il;
    }
    __syncthreads();

    // ---- MFMA FIR + post-MLP epilogue, 2 tiles of 256 outputs per wave ----
#pragma unroll
    for (int tt = 0; tt < 2; ++tt) {
        const int base_o = 512 * wv + 256 * tt;
        const int i1 = base_o + 16 * jA + 8 * kg;          // B1 elements
        const half8 Bxr_h = *(const half8*)&s_rh[i1];
        const half8 Bxi_h = *(const half8*)&s_ih[i1];
        const half8 Bxr_l = *(const half8*)&s_rl[i1];
        const half8 Bxi_l = *(const half8*)&s_il[i1];
        const int i2 = base_o + 16 * jA + 32 + 8 * (kg & 1); // B2 mixed elements
        const _Float16* srcH = (kg < 2) ? s_rh : s_ih;
        const _Float16* srcL = (kg < 2) ? s_rl : s_il;
        const half8 Bmx_h = *(const half8*)&srcH[i2];
        const half8 Bmx_l = *(const half8*)&srcL[i2];

        floatx4 accr = {0.f, 0.f, 0.f, 0.f};
        floatx4 acci = {0.f, 0.f, 0.f, 0.f};
        // term (w_hi, x_hi)
        accr = MFMA16(A1r_h,  Bxr_h, accr);  acci = MFMA16(A1i_h,  Bxr_h, acci);
        accr = MFMA16(A1mi_h, Bxi_h, accr);  acci = MFMA16(A1r_h,  Bxi_h, acci);
        accr = MFMA16(A2r_h,  Bmx_h, accr);  acci = MFMA16(A2i_h,  Bmx_h, acci);
        // term (w_hi, x_lo)
        accr = MFMA16(A1r_h,  Bxr_l, accr);  acci = MFMA16(A1i_h,  Bxr_l, acci);
        accr = MFMA16(A1mi_h, Bxi_l, accr);  acci = MFMA16(A1r_h,  Bxi_l, acci);
        accr = MFMA16(A2r_h,  Bmx_l, accr);  acci = MFMA16(A2i_h,  Bmx_l, acci);
        // term (w_lo, x_hi)
        accr = MFMA16(A1r_l,  Bxr_h, accr);  acci = MFMA16(A1i_l,  Bxr_h, acci);
        accr = MFMA16(A1mi_l, Bxi_h, accr);  acci = MFMA16(A1r_l,  Bxi_h, acci);
        accr = MFMA16(A2r_l,  Bmx_h, accr);  acci = MFMA16(A2i_l,  Bmx_h, acci);

        // epilogue: D row j = 4*kg + r, col n = jA -> o = base_o + 16*jA + 4*kg + r
        const int obase = tstart + base_o + 16 * jA + 4 * kg;
#pragma unroll
        for (int r = 0; r < 4; ++r) {
            const int o = obase + r;
            if (o < OUTW) {
                const float zr  = accr[r], zi = acci[r];
                const float zsq = fmaf(zr, zr, zi * zi);
                const float rs  = (zsq > 0.f) ? __builtin_amdgcn_rsqf(zsq) : 0.f;
                const float zmag = zsq * rs;
                float zm = b2p;
#pragma unroll
                for (int f = 0; f < 8; ++f) {
                    const float gfv = fmaf(zmag, w1p[f], b1p[f]);
                    zm = fmaf(fmaxf(gfv, 0.f), w2p[f], zm);
                }
                const float t = SCALE_V * zm * rs;
                float2 o2;
                o2.x = (zsq > 0.f) ? t * zr : SCALE_V * zm;
                o2.y = t * zi;
                *(float2*)&out[((long)brow * OUTW + o) * 2] = o2;
            }
        }
    }
}

extern "C" void kernel_launch(void* const* d_in, const int* in_sizes, int n_in,
                              void* d_out, int out_size, void* d_ws, size_t ws_size,
                              hipStream_t stream) {
    const int blocks_w = (OUTW + TILE - 1) / TILE;   // 128
    dim3 grid(blocks_w, 16);
    fused_hammer_mfma<<<grid, 256, 0, stream>>>(
        (const float*)d_in[0], (const float*)d_in[1],
        (const float*)d_in[2], (const float*)d_in[3],
        (const float*)d_in[4], (const float*)d_in[5],
        (const float*)d_in[6], (const float*)d_in[7],
        (const float*)d_in[8], (const float*)d_in[9],
        (float*)d_out);
}

// Round 5
// 112.715 us; speedup vs baseline: 1.1528x; 1.0105x over previous
//
#include <hip/hip_runtime.h>

#define TILE   2048
#define NS     2096                 // staged elements per block (TILE + 48)
#define WIDTH  262144
#define OUTW   (WIDTH - 31)         // 262113
#define SCALE_V 0.17782794100389229f // sqrt(10^(-15/10))

#define TBL_N    2048
#define TBL_MAX  10.0f
#define TBL_SCL  (TBL_N / TBL_MAX)   // 204.8

typedef _Float16 half8  __attribute__((ext_vector_type(8)));
typedef _Float16 half4v __attribute__((ext_vector_type(4)));
typedef float    floatx4 __attribute__((ext_vector_type(4)));

__device__ __forceinline__ float wload(const float* __restrict__ w, int t) {
    return (t >= 0 && t < 32) ? w[t] : 0.0f;
}

#define MFMA16(A, B, C) __builtin_amdgcn_mfma_f32_16x16x32_f16((A), (B), (C), 0, 0, 0)

// ---- table fill: s(mag) = sum_f w2[f]*tanh(w1[f]*mag)/mag, entries (s, ds) ----
__device__ __forceinline__ float s_of_mag(float mag, const float* w1, const float* w2) {
    if (mag == 0.0f) {
        float s = 0.f;
#pragma unroll
        for (int f = 0; f < 8; ++f) s = fmaf(w2[f], w1[f], s);   // tanh'(0)=1
        return s;
    }
    float m = 0.f;
#pragma unroll
    for (int f = 0; f < 8; ++f) m = fmaf(w2[f], tanhf(w1[f] * mag), m);
    return m / mag;
}

__global__ void fill_s_table(const float* __restrict__ w1_pre,
                             const float* __restrict__ w2_pre,
                             float2* __restrict__ tbl)
{
    const int i = blockIdx.x * 256 + threadIdx.x;   // 0..2047
    if (i >= TBL_N) return;
    float w1[8], w2[8];
#pragma unroll
    for (int f = 0; f < 8; ++f) { w1[f] = w1_pre[f]; w2[f] = w2_pre[f]; }
    const float m0 = (float)i       * (1.0f / TBL_SCL);
    const float m1 = (float)(i + 1) * (1.0f / TBL_SCL);
    const float s0 = s_of_mag(m0, w1, w2);
    const float s1 = s_of_mag(m1, w1, w2);
    tbl[i] = make_float2(s0, s1 - s0);
}

// FIR as Toeplitz MFMA (see R3): 3 precision terms (wh*xh + wh*xl + wl*xh),
// chunk2 packed as one mixed-B MFMA. Pre-MLP replaced by LDS lerp table.
__global__ __launch_bounds__(256) void fused_hammer_mfma(
    const float* __restrict__ xr_g,   const float* __restrict__ xi_g,
    const float* __restrict__ w1_pre, const float* __restrict__ w2_pre,
    const float* __restrict__ wfr,    const float* __restrict__ wfi,
    const float* __restrict__ w1_post,const float* __restrict__ b1_post,
    const float* __restrict__ w2_post,const float* __restrict__ b2_post,
    const float2* __restrict__ tbl_g,
    float* __restrict__ out)
{
    __shared__ __align__(16) _Float16 s_rh[NS];
    __shared__ __align__(16) _Float16 s_rl[NS];
    __shared__ __align__(16) _Float16 s_ih[NS];
    __shared__ __align__(16) _Float16 s_il[NS];
    __shared__ __align__(16) float2   s_tab[TBL_N];

    const int tid    = threadIdx.x;
    const int lane   = tid & 63;
    const int wv     = tid >> 6;
    const int tstart = blockIdx.x * TILE;
    const int brow   = blockIdx.y;
    const long rowbase = (long)brow * WIDTH;

    // ---- load s-table into LDS (2048 float2 = 1024 float4; 4 per thread) ----
    {
        const float4* src = (const float4*)tbl_g;
#pragma unroll
        for (int q = 0; q < 4; ++q) {
            const int idx = 4 * tid + q;            // float4 index, 0..1023
            ((float4*)s_tab)[idx] = src[idx];
        }
    }

    // ---- post-MLP uniform weights ----
    float w1p[8], b1p[8], w2p[8];
#pragma unroll
    for (int f = 0; f < 8; ++f) { w1p[f] = w1_post[f]; b1p[f] = b1_post[f]; w2p[f] = w2_post[f]; }
    const float b2p = b2_post[0];

    // ---- build Toeplitz weight fragments (hi/lo f16), once per lane ----
    const int jA = lane & 15;
    const int kg = lane >> 4;
    half8 A1r_h, A1r_l, A1mi_h, A1mi_l, A1i_h, A1i_l, A2r_h, A2r_l, A2i_h, A2i_l;
#pragma unroll
    for (int jj = 0; jj < 8; ++jj) {
        const int k  = 8 * kg + jj;
        const int t1 = k - jA;
        const float wr1 = wload(wfr, t1);
        const float wi1 = wload(wfi, t1);
        const int t2 = (k < 16) ? (k + 32 - jA) : (k + 16 - jA);
        const float wr2 = wload(wfr, t2);
        const float wi2 = wload(wfi, t2);
        const float a2r = (k < 16) ? wr2 : -wi2;   // zr second chunk: [wr | -wi]
        const float a2i = (k < 16) ? wi2 : wr2;    // zi second chunk: [wi |  wr]
        _Float16 h;
        h = (_Float16)wr1;   A1r_h[jj]  = h; A1r_l[jj]  = (_Float16)(wr1 - (float)h);
        h = (_Float16)(-wi1);A1mi_h[jj] = h; A1mi_l[jj] = (_Float16)(-wi1 - (float)h);
        h = (_Float16)wi1;   A1i_h[jj]  = h; A1i_l[jj]  = (_Float16)(wi1 - (float)h);
        h = (_Float16)a2r;   A2r_h[jj]  = h; A2r_l[jj]  = (_Float16)(a2r - (float)h);
        h = (_Float16)a2i;   A2i_h[jj]  = h; A2i_l[jj]  = (_Float16)(a2i - (float)h);
    }

    __syncthreads();   // table visible before staging uses it

    // ---- stage pre-MLP output into LDS as f16 hi/lo (table lerp) ----
    for (int p = tid; p < NS / 4; p += 256) {
        const int g = tstart + 4 * p;
        float4 vr, vi;
        if (g + 3 < WIDTH) {
            vr = *(const float4*)(xr_g + rowbase + g);
            vi = *(const float4*)(xi_g + rowbase + g);
        } else {
            float rr[4], ii[4];
#pragma unroll
            for (int e = 0; e < 4; ++e) {
                const int gg = g + e;
                rr[e] = (gg < WIDTH) ? xr_g[rowbase + gg] : 0.f;
                ii[e] = (gg < WIDTH) ? xi_g[rowbase + gg] : 0.f;
            }
            vr = make_float4(rr[0], rr[1], rr[2], rr[3]);
            vi = make_float4(ii[0], ii[1], ii[2], ii[3]);
        }
        const float* vrf = &vr.x;
        const float* vif = &vi.x;
        half4v rh, rl, ih, il;
#pragma unroll
        for (int e = 0; e < 4; ++e) {
            const float r  = vrf[e], im = vif[e];
            const float sq  = fmaf(r, r, im * im);
            const float mag = __builtin_sqrtf(sq);
            const float t   = fminf(mag * TBL_SCL, (float)(TBL_N - 2) + 0.999f);
            const int   i0  = (int)t;
            const float frac = t - (float)i0;
            const float2 en = s_tab[i0];
            const float s   = fmaf(frac, en.y, en.x);   // lerp: s(mag)
            const float xhr = s * r;
            const float xhi = s * im;
            const _Float16 hr = (_Float16)xhr;
            const _Float16 hi = (_Float16)xhi;
            rh[e] = hr; rl[e] = (_Float16)(xhr - (float)hr);
            ih[e] = hi; il[e] = (_Float16)(xhi - (float)hi);
        }
        *(half4v*)&s_rh[4 * p] = rh;
        *(half4v*)&s_rl[4 * p] = rl;
        *(half4v*)&s_ih[4 * p] = ih;
        *(half4v*)&s_il[4 * p] = il;
    }
    __syncthreads();

    // ---- MFMA FIR + post-MLP epilogue, 2 tiles of 256 outputs per wave ----
#pragma unroll
    for (int tt = 0; tt < 2; ++tt) {
        const int base_o = 512 * wv + 256 * tt;
        const int i1 = base_o + 16 * jA + 8 * kg;          // B1 elements
        const half8 Bxr_h = *(const half8*)&s_rh[i1];
        const half8 Bxi_h = *(const half8*)&s_ih[i1];
        const half8 Bxr_l = *(const half8*)&s_rl[i1];
        const half8 Bxi_l = *(const half8*)&s_il[i1];
        const int i2 = base_o + 16 * jA + 32 + 8 * (kg & 1); // B2 mixed elements
        const _Float16* srcH = (kg < 2) ? s_rh : s_ih;
        const _Float16* srcL = (kg < 2) ? s_rl : s_il;
        const half8 Bmx_h = *(const half8*)&srcH[i2];
        const half8 Bmx_l = *(const half8*)&srcL[i2];

        floatx4 accr = {0.f, 0.f, 0.f, 0.f};
        floatx4 acci = {0.f, 0.f, 0.f, 0.f};
        accr = MFMA16(A1r_h,  Bxr_h, accr);  acci = MFMA16(A1i_h,  Bxr_h, acci);
        accr = MFMA16(A1mi_h, Bxi_h, accr);  acci = MFMA16(A1r_h,  Bxi_h, acci);
        accr = MFMA16(A2r_h,  Bmx_h, accr);  acci = MFMA16(A2i_h,  Bmx_h, acci);
        accr = MFMA16(A1r_h,  Bxr_l, accr);  acci = MFMA16(A1i_h,  Bxr_l, acci);
        accr = MFMA16(A1mi_h, Bxi_l, accr);  acci = MFMA16(A1r_h,  Bxi_l, acci);
        accr = MFMA16(A2r_h,  Bmx_l, accr);  acci = MFMA16(A2i_h,  Bmx_l, acci);
        accr = MFMA16(A1r_l,  Bxr_h, accr);  acci = MFMA16(A1i_l,  Bxr_h, acci);
        accr = MFMA16(A1mi_l, Bxi_h, accr);  acci = MFMA16(A1r_l,  Bxi_h, acci);
        accr = MFMA16(A2r_l,  Bmx_h, accr);  acci = MFMA16(A2i_l,  Bmx_h, acci);

        const int obase = tstart + base_o + 16 * jA + 4 * kg;
#pragma unroll
        for (int r = 0; r < 4; ++r) {
            const int o = obase + r;
            if (o < OUTW) {
                const float zr  = accr[r], zi = acci[r];
                const float zsq = fmaf(zr, zr, zi * zi);
                const float rs  = (zsq > 0.f) ? __builtin_amdgcn_rsqf(zsq) : 0.f;
                const float zmag = zsq * rs;
                float zm = b2p;
#pragma unroll
                for (int f = 0; f < 8; ++f) {
                    const float gfv = fmaf(zmag, w1p[f], b1p[f]);
                    zm = fmaf(fmaxf(gfv, 0.f), w2p[f], zm);
                }
                const float t = SCALE_V * zm * rs;
                float2 o2;
                o2.x = (zsq > 0.f) ? t * zr : SCALE_V * zm;
                o2.y = t * zi;
                *(float2*)&out[((long)brow * OUTW + o) * 2] = o2;
            }
        }
    }
}

extern "C" void kernel_launch(void* const* d_in, const int* in_sizes, int n_in,
                              void* d_out, int out_size, void* d_ws, size_t ws_size,
                              hipStream_t stream) {
    float2* tbl = (float2*)d_ws;    // 16 KB of workspace
    fill_s_table<<<dim3((TBL_N + 255) / 256), 256, 0, stream>>>(
        (const float*)d_in[2], (const float*)d_in[3], tbl);

    const int blocks_w = (OUTW + TILE - 1) / TILE;   // 128
    dim3 grid(blocks_w, 16);
    fused_hammer_mfma<<<grid, 256, 0, stream>>>(
        (const float*)d_in[0], (const float*)d_in[1],
        (const float*)d_in[2], (const float*)d_in[3],
        (const float*)d_in[4], (const float*)d_in[5],
        (const float*)d_in[6], (const float*)d_in[7],
        (const float*)d_in[8], (const float*)d_in[9],
        tbl,
        (float*)d_out);
}

// Round 6
// 111.463 us; speedup vs baseline: 1.1657x; 1.0112x over previous
//
#include <hip/hip_runtime.h>

#define TILE   2048                 // outputs per block
#define WTILE  512                  // outputs per wave
#define NSW    560                  // staged elements per wave (512 + 48 halo)
#define WIDTH  262144
#define OUTW   (WIDTH - 31)         // 262113
#define SCALE_V 0.17782794100389229f // sqrt(10^(-15/10))

#define TBL_N    1024
#define TBL_MAX  10.0f
#define TBL_SCL  (TBL_N / TBL_MAX)   // 102.4

typedef _Float16 half8  __attribute__((ext_vector_type(8)));
typedef _Float16 half4v __attribute__((ext_vector_type(4)));
typedef float    floatx4 __attribute__((ext_vector_type(4)));

__device__ __forceinline__ float wload(const float* __restrict__ w, int t) {
    return (t >= 0 && t < 32) ? w[t] : 0.0f;
}

#define MFMA16(A, B, C) __builtin_amdgcn_mfma_f32_16x16x32_f16((A), (B), (C), 0, 0, 0)

// ---- table fill: s(mag) = sum_f w2[f]*tanh(w1[f]*mag)/mag, entries (s, ds) ----
__device__ __forceinline__ float s_of_mag(float mag, const float* w1, const float* w2) {
    if (mag == 0.0f) {
        float s = 0.f;
#pragma unroll
        for (int f = 0; f < 8; ++f) s = fmaf(w2[f], w1[f], s);   // tanh'(0)=1
        return s;
    }
    float m = 0.f;
#pragma unroll
    for (int f = 0; f < 8; ++f) m = fmaf(w2[f], tanhf(w1[f] * mag), m);
    return m / mag;
}

__global__ void fill_s_table(const float* __restrict__ w1_pre,
                             const float* __restrict__ w2_pre,
                             float2* __restrict__ tbl)
{
    const int i = blockIdx.x * 256 + threadIdx.x;   // 0..1023
    if (i >= TBL_N) return;
    float w1[8], w2[8];
#pragma unroll
    for (int f = 0; f < 8; ++f) { w1[f] = w1_pre[f]; w2[f] = w2_pre[f]; }
    const float m0 = (float)i       * (1.0f / TBL_SCL);
    const float m1 = (float)(i + 1) * (1.0f / TBL_SCL);
    const float s0 = s_of_mag(m0, w1, w2);
    const float s1 = s_of_mag(m1, w1, w2);
    tbl[i] = make_float2(s0, s1 - s0);
}

// Wave-private pipeline: each wave stages its own 512-output slice (+48 halo)
// into a private LDS strip, waits lgkmcnt(0) (no block barrier), then runs the
// Toeplitz MFMA FIR (3 precision terms) + post-MLP epilogue on it. Only one
// __syncthreads in the kernel (after the shared s-table load).
__global__ __launch_bounds__(256) void fused_hammer_mfma(
    const float* __restrict__ xr_g,   const float* __restrict__ xi_g,
    const float* __restrict__ w1_pre, const float* __restrict__ w2_pre,
    const float* __restrict__ wfr,    const float* __restrict__ wfi,
    const float* __restrict__ w1_post,const float* __restrict__ b1_post,
    const float* __restrict__ w2_post,const float* __restrict__ b2_post,
    const float2* __restrict__ tbl_g,
    float* __restrict__ out)
{
    __shared__ __align__(16) _Float16 s_rh[4][NSW];
    __shared__ __align__(16) _Float16 s_rl[4][NSW];
    __shared__ __align__(16) _Float16 s_ih[4][NSW];
    __shared__ __align__(16) _Float16 s_il[4][NSW];
    __shared__ __align__(16) float2   s_tab[TBL_N];

    const int tid    = threadIdx.x;
    const int lane   = tid & 63;
    const int wv     = tid >> 6;
    const int tstart = blockIdx.x * TILE;
    const int wstart = tstart + wv * WTILE;   // this wave's output base within row
    const int brow   = blockIdx.y;
    const long rowbase = (long)brow * WIDTH;

    // ---- load s-table into LDS (1024 float2 = 512 float4; 2 per thread) ----
    {
        const float4* src = (const float4*)tbl_g;
#pragma unroll
        for (int q = 0; q < 2; ++q) {
            const int idx = 2 * tid + q;            // 0..511
            ((float4*)s_tab)[idx] = src[idx];
        }
    }

    // ---- post-MLP uniform weights ----
    float w1p[8], b1p[8], w2p[8];
#pragma unroll
    for (int f = 0; f < 8; ++f) { w1p[f] = w1_post[f]; b1p[f] = b1_post[f]; w2p[f] = w2_post[f]; }
    const float b2p = b2_post[0];

    // ---- build Toeplitz weight fragments (hi/lo f16), once per lane ----
    const int jA = lane & 15;
    const int kg = lane >> 4;
    half8 A1r_h, A1r_l, A1mi_h, A1mi_l, A1i_h, A1i_l, A2r_h, A2r_l, A2i_h, A2i_l;
#pragma unroll
    for (int jj = 0; jj < 8; ++jj) {
        const int k  = 8 * kg + jj;
        const int t1 = k - jA;
        const float wr1 = wload(wfr, t1);
        const float wi1 = wload(wfi, t1);
        const int t2 = (k < 16) ? (k + 32 - jA) : (k + 16 - jA);
        const float wr2 = wload(wfr, t2);
        const float wi2 = wload(wfi, t2);
        const float a2r = (k < 16) ? wr2 : -wi2;   // zr second chunk: [wr | -wi]
        const float a2i = (k < 16) ? wi2 : wr2;    // zi second chunk: [wi |  wr]
        _Float16 h;
        h = (_Float16)wr1;   A1r_h[jj]  = h; A1r_l[jj]  = (_Float16)(wr1 - (float)h);
        h = (_Float16)(-wi1);A1mi_h[jj] = h; A1mi_l[jj] = (_Float16)(-wi1 - (float)h);
        h = (_Float16)wi1;   A1i_h[jj]  = h; A1i_l[jj]  = (_Float16)(wi1 - (float)h);
        h = (_Float16)a2r;   A2r_h[jj]  = h; A2r_l[jj]  = (_Float16)(a2r - (float)h);
        h = (_Float16)a2i;   A2i_h[jj]  = h; A2i_l[jj]  = (_Float16)(a2i - (float)h);
    }

    __syncthreads();   // s_tab visible to all waves; only barrier in the kernel

    // ---- stage this wave's slice into its private LDS strip (table lerp) ----
    for (int p = lane; p < NSW / 4; p += 64) {    // 140 float4-groups
        const int g = wstart + 4 * p;
        float4 vr, vi;
        if (g + 3 < WIDTH) {
            vr = *(const float4*)(xr_g + rowbase + g);
            vi = *(const float4*)(xi_g + rowbase + g);
        } else {                                   // only the last block
            float rr[4], ii[4];
#pragma unroll
            for (int e = 0; e < 4; ++e) {
                const int gg = g + e;
                rr[e] = (gg < WIDTH) ? xr_g[rowbase + gg] : 0.f;
                ii[e] = (gg < WIDTH) ? xi_g[rowbase + gg] : 0.f;
            }
            vr = make_float4(rr[0], rr[1], rr[2], rr[3]);
            vi = make_float4(ii[0], ii[1], ii[2], ii[3]);
        }
        const float* vrf = &vr.x;
        const float* vif = &vi.x;
        half4v rh, rl, ih, il;
#pragma unroll
        for (int e = 0; e < 4; ++e) {
            const float r  = vrf[e], im = vif[e];
            const float sq  = fmaf(r, r, im * im);
            const float mag = __builtin_sqrtf(sq);
            const float t   = fminf(mag * TBL_SCL, (float)(TBL_N - 2) + 0.999f);
            const int   i0  = (int)t;
            const float frac = t - (float)i0;
            const float2 en = s_tab[i0];
            const float s   = fmaf(frac, en.y, en.x);   // lerp: s(mag)
            const float xhr = s * r;
            const float xhi = s * im;
            const _Float16 hr = (_Float16)xhr;
            const _Float16 hi = (_Float16)xhi;
            rh[e] = hr; rl[e] = (_Float16)(xhr - (float)hr);
            ih[e] = hi; il[e] = (_Float16)(xhi - (float)hi);
        }
        *(half4v*)&s_rh[wv][4 * p] = rh;
        *(half4v*)&s_rl[wv][4 * p] = rl;
        *(half4v*)&s_ih[wv][4 * p] = ih;
        *(half4v*)&s_il[wv][4 * p] = il;
    }
    // wave-private LDS: own writes complete -> readable, no block barrier
    asm volatile("s_waitcnt lgkmcnt(0)" ::: "memory");

    const bool row_aligned = ((brow & 1) == 0);   // even brow -> 16B-aligned stores

    // ---- MFMA FIR + post-MLP epilogue, 2 tiles of 256 outputs per wave ----
#pragma unroll
    for (int tt = 0; tt < 2; ++tt) {
        const int base_o = 256 * tt;
        const int i1 = base_o + 16 * jA + 8 * kg;          // B1 elements
        const half8 Bxr_h = *(const half8*)&s_rh[wv][i1];
        const half8 Bxi_h = *(const half8*)&s_ih[wv][i1];
        const half8 Bxr_l = *(const half8*)&s_rl[wv][i1];
        const half8 Bxi_l = *(const half8*)&s_il[wv][i1];
        const int i2 = base_o + 16 * jA + 32 + 8 * (kg & 1); // B2 mixed elements
        const _Float16* srcH = (kg < 2) ? s_rh[wv] : s_ih[wv];
        const _Float16* srcL = (kg < 2) ? s_rl[wv] : s_il[wv];
        const half8 Bmx_h = *(const half8*)&srcH[i2];
        const half8 Bmx_l = *(const half8*)&srcL[i2];

        floatx4 accr = {0.f, 0.f, 0.f, 0.f};
        floatx4 acci = {0.f, 0.f, 0.f, 0.f};
        accr = MFMA16(A1r_h,  Bxr_h, accr);  acci = MFMA16(A1i_h,  Bxr_h, acci);
        accr = MFMA16(A1mi_h, Bxi_h, accr);  acci = MFMA16(A1r_h,  Bxi_h, acci);
        accr = MFMA16(A2r_h,  Bmx_h, accr);  acci = MFMA16(A2i_h,  Bmx_h, acci);
        accr = MFMA16(A1r_h,  Bxr_l, accr);  acci = MFMA16(A1i_h,  Bxr_l, acci);
        accr = MFMA16(A1mi_h, Bxi_l, accr);  acci = MFMA16(A1r_h,  Bxi_l, acci);
        accr = MFMA16(A2r_h,  Bmx_l, accr);  acci = MFMA16(A2i_h,  Bmx_l, acci);
        accr = MFMA16(A1r_l,  Bxr_h, accr);  acci = MFMA16(A1i_l,  Bxr_h, acci);
        accr = MFMA16(A1mi_l, Bxi_h, accr);  acci = MFMA16(A1r_l,  Bxi_h, acci);
        accr = MFMA16(A2r_l,  Bmx_h, accr);  acci = MFMA16(A2i_l,  Bmx_h, acci);

        // epilogue: lane owns 4 CONSECUTIVE outputs obase..obase+3
        const int obase = wstart + base_o + 16 * jA + 4 * kg;
        float ox[8];
#pragma unroll
        for (int r = 0; r < 4; ++r) {
            const float zr  = accr[r], zi = acci[r];
            const float zsq = fmaf(zr, zr, zi * zi);
            const float rs  = (zsq > 0.f) ? __builtin_amdgcn_rsqf(zsq) : 0.f;
            const float zmag = zsq * rs;
            float zm = b2p;
#pragma unroll
            for (int f = 0; f < 8; ++f) {
                const float gfv = fmaf(zmag, w1p[f], b1p[f]);
                zm = fmaf(fmaxf(gfv, 0.f), w2p[f], zm);
            }
            const float t = SCALE_V * zm * rs;
            ox[2 * r]     = (zsq > 0.f) ? t * zr : SCALE_V * zm;
            ox[2 * r + 1] = t * zi;
        }
        float* po = &out[((long)brow * OUTW + obase) * 2];
        if (obase + 3 < OUTW) {
            if (row_aligned) {
                *(float4*)(po)     = make_float4(ox[0], ox[1], ox[2], ox[3]);
                *(float4*)(po + 4) = make_float4(ox[4], ox[5], ox[6], ox[7]);
            } else {
#pragma unroll
                for (int r = 0; r < 4; ++r)
                    *(float2*)(po + 2 * r) = make_float2(ox[2 * r], ox[2 * r + 1]);
            }
        } else {
#pragma unroll
            for (int r = 0; r < 4; ++r)
                if (obase + r < OUTW)
                    *(float2*)(po + 2 * r) = make_float2(ox[2 * r], ox[2 * r + 1]);
        }
    }
}

extern "C" void kernel_launch(void* const* d_in, const int* in_sizes, int n_in,
                              void* d_out, int out_size, void* d_ws, size_t ws_size,
                              hipStream_t stream) {
    float2* tbl = (float2*)d_ws;    // 8 KB of workspace
    fill_s_table<<<dim3((TBL_N + 255) / 256), 256, 0, stream>>>(
        (const float*)d_in[2], (const float*)d_in[3], tbl);

    const int blocks_w = (OUTW + TILE - 1) / TILE;   // 128
    dim3 grid(blocks_w, 16);
    fused_hammer_mfma<<<grid, 256, 0, stream>>>(
        (const float*)d_in[0], (const float*)d_in[1],
        (const float*)d_in[2], (const float*)d_in[3],
        (const float*)d_in[4], (const float*)d_in[5],
        (const float*)d_in[6], (const float*)d_in[7],
        (const float*)d_in[8], (const float*)d_in[9],
        tbl,
        (float*)d_out);
}

// Round 7
// 111.247 us; speedup vs baseline: 1.1680x; 1.0019x over previous
//
#include <hip/hip_runtime.h>

#define WIDTH  262144
#define OUTW   (WIDTH - 31)         // 262113
#define WTILE  512                  // outputs per slice
#define NSW    560                  // staged elements per slice (512 + 48 halo)
#define SCALE_V 0.17782794100389229f // sqrt(10^(-15/10))

#define TBL_N    1024
#define TBL_MAX  10.0f
#define TBL_SCL  (TBL_N / TBL_MAX)   // 102.4

typedef _Float16 half8  __attribute__((ext_vector_type(8)));
typedef _Float16 half4v __attribute__((ext_vector_type(4)));
typedef float    floatx4 __attribute__((ext_vector_type(4)));

__device__ __forceinline__ float wload(const float* __restrict__ w, int t) {
    return (t >= 0 && t < 32) ? w[t] : 0.0f;
}

#define MFMA16(A, B, C) __builtin_amdgcn_mfma_f32_16x16x32_f16((A), (B), (C), 0, 0, 0)

// ---- table fill: s(mag) = sum_f w2[f]*tanh(w1[f]*mag)/mag, entries (s, ds) ----
__device__ __forceinline__ float s_of_mag(float mag, const float* w1, const float* w2) {
    if (mag == 0.0f) {
        float s = 0.f;
#pragma unroll
        for (int f = 0; f < 8; ++f) s = fmaf(w2[f], w1[f], s);   // tanh'(0)=1
        return s;
    }
    float m = 0.f;
#pragma unroll
    for (int f = 0; f < 8; ++f) m = fmaf(w2[f], tanhf(w1[f] * mag), m);
    return m / mag;
}

__global__ void fill_s_table(const float* __restrict__ w1_pre,
                             const float* __restrict__ w2_pre,
                             float2* __restrict__ tbl)
{
    const int i = blockIdx.x * 256 + threadIdx.x;   // 0..1023
    if (i >= TBL_N) return;
    float w1[8], w2[8];
#pragma unroll
    for (int f = 0; f < 8; ++f) { w1[f] = w1_pre[f]; w2[f] = w2_pre[f]; }
    const float m0 = (float)i       * (1.0f / TBL_SCL);
    const float m1 = (float)(i + 1) * (1.0f / TBL_SCL);
    const float s0 = s_of_mag(m0, w1, w2);
    const float s1 = s_of_mag(m1, w1, w2);
    tbl[i] = make_float2(s0, s1 - s0);
}

// Software-pipelined wave-private pipeline: each wave handles 2 consecutive
// 512-output slices. Slice-0 global loads are issued FIRST (latency covered by
// table load + Toeplitz fragment build); slice-1 loads are prefetched before
// slice-0's MFMA+epilogue (latency covered by compute). Out-of-range staging
// positions are clamped (branchless) — they only feed outputs >= OUTW, which
// are clipped at store. One __syncthreads total (s_tab visibility).
__global__ __launch_bounds__(256, 4) void fused_hammer_mfma(
    const float* __restrict__ xr_g,   const float* __restrict__ xi_g,
    const float* __restrict__ w1_pre, const float* __restrict__ w2_pre,
    const float* __restrict__ wfr,    const float* __restrict__ wfi,
    const float* __restrict__ w1_post,const float* __restrict__ b1_post,
    const float* __restrict__ w2_post,const float* __restrict__ b2_post,
    const float2* __restrict__ tbl_g,
    float* __restrict__ out)
{
    __shared__ __align__(16) _Float16 s_rh[4][NSW];
    __shared__ __align__(16) _Float16 s_rl[4][NSW];
    __shared__ __align__(16) _Float16 s_ih[4][NSW];
    __shared__ __align__(16) _Float16 s_il[4][NSW];
    __shared__ __align__(16) float2   s_tab[TBL_N];

    const int tid    = threadIdx.x;
    const int lane   = tid & 63;
    const int wv     = tid >> 6;
    const int brow   = blockIdx.y;
    const long rowbase = (long)brow * WIDTH;
    const int wbase  = blockIdx.x * 4096 + wv * 1024;  // wave's first slice offset

    // ---- prefetch slice 0 (2 float4-pairs per lane; branchless clamp) ----
    const int g0 = min(wbase       + 4 * lane, WIDTH - 4);
    const int g1 = min(wbase + 256 + 4 * lane, WIDTH - 4);
    float4 p_r0 = *(const float4*)(xr_g + rowbase + g0);
    float4 p_i0 = *(const float4*)(xi_g + rowbase + g0);
    float4 p_r1 = *(const float4*)(xr_g + rowbase + g1);
    float4 p_i1 = *(const float4*)(xi_g + rowbase + g1);

    // ---- load s-table into LDS (1024 float2 = 512 float4; 2 per thread) ----
    {
        const float4* src = (const float4*)tbl_g;
#pragma unroll
        for (int q = 0; q < 2; ++q) {
            const int idx = 2 * tid + q;            // 0..511
            ((float4*)s_tab)[idx] = src[idx];
        }
    }

    // ---- post-MLP uniform weights ----
    float w1p[8], b1p[8], w2p[8];
#pragma unroll
    for (int f = 0; f < 8; ++f) { w1p[f] = w1_post[f]; b1p[f] = b1_post[f]; w2p[f] = w2_post[f]; }
    const float b2p = b2_post[0];

    // ---- build Toeplitz weight fragments (hi/lo f16), once per lane ----
    const int jA = lane & 15;
    const int kg = lane >> 4;
    half8 A1r_h, A1r_l, A1mi_h, A1mi_l, A1i_h, A1i_l, A2r_h, A2r_l, A2i_h, A2i_l;
#pragma unroll
    for (int jj = 0; jj < 8; ++jj) {
        const int k  = 8 * kg + jj;
        const int t1 = k - jA;
        const float wr1 = wload(wfr, t1);
        const float wi1 = wload(wfi, t1);
        const int t2 = (k < 16) ? (k + 32 - jA) : (k + 16 - jA);
        const float wr2 = wload(wfr, t2);
        const float wi2 = wload(wfi, t2);
        const float a2r = (k < 16) ? wr2 : -wi2;   // zr second chunk: [wr | -wi]
        const float a2i = (k < 16) ? wi2 : wr2;    // zi second chunk: [wi |  wr]
        _Float16 h;
        h = (_Float16)wr1;   A1r_h[jj]  = h; A1r_l[jj]  = (_Float16)(wr1 - (float)h);
        h = (_Float16)(-wi1);A1mi_h[jj] = h; A1mi_l[jj] = (_Float16)(-wi1 - (float)h);
        h = (_Float16)wi1;   A1i_h[jj]  = h; A1i_l[jj]  = (_Float16)(wi1 - (float)h);
        h = (_Float16)a2r;   A2r_h[jj]  = h; A2r_l[jj]  = (_Float16)(a2r - (float)h);
        h = (_Float16)a2i;   A2i_h[jj]  = h; A2i_l[jj]  = (_Float16)(a2i - (float)h);
    }

    __syncthreads();   // s_tab visible to all waves; only barrier in the kernel

    const bool row_aligned = ((brow & 1) == 0);   // even brow -> 16B-aligned stores

    // stage one float4-pair into strip group p (table lerp + f16 hi/lo split)
#define STAGE4(VR, VI, P)                                                     \
    do {                                                                      \
        const float* vrf = &(VR).x;                                           \
        const float* vif = &(VI).x;                                           \
        half4v rh_, rl_, ih_, il_;                                            \
        _Pragma("unroll")                                                     \
        for (int e = 0; e < 4; ++e) {                                         \
            const float r  = vrf[e], im = vif[e];                             \
            const float sq  = fmaf(r, r, im * im);                            \
            const float mag = __builtin_sqrtf(sq);                            \
            const float t   = fminf(mag * TBL_SCL, (float)(TBL_N - 2) + 0.999f); \
            const int   i0  = (int)t;                                         \
            const float frac = t - (float)i0;                                 \
            const float2 en = s_tab[i0];                                      \
            const float s   = fmaf(frac, en.y, en.x);                         \
            const float xhr = s * r;                                          \
            const float xhi = s * im;                                         \
            const _Float16 hr = (_Float16)xhr;                                \
            const _Float16 hi = (_Float16)xhi;                                \
            rh_[e] = hr; rl_[e] = (_Float16)(xhr - (float)hr);                \
            ih_[e] = hi; il_[e] = (_Float16)(xhi - (float)hi);                \
        }                                                                     \
        *(half4v*)&s_rh[wv][4 * (P)] = rh_;                                   \
        *(half4v*)&s_rl[wv][4 * (P)] = rl_;                                   \
        *(half4v*)&s_ih[wv][4 * (P)] = ih_;                                   \
        *(half4v*)&s_il[wv][4 * (P)] = il_;                                   \
    } while (0)

#pragma unroll
    for (int q = 0; q < 2; ++q) {
        const int wstart = wbase + q * WTILE;

        // halo pair (strip groups 128..139, lanes 0..11 only)
        float4 h_r, h_i;
        if (lane < 12) {
            const int g2 = min(wstart + 512 + 4 * lane, WIDTH - 4);
            h_r = *(const float4*)(xr_g + rowbase + g2);
            h_i = *(const float4*)(xi_g + rowbase + g2);
        }

        STAGE4(p_r0, p_i0, lane);
        STAGE4(p_r1, p_i1, 64 + lane);

        if (q == 0) {   // prefetch slice 1 while slice 0 computes below
            const int n0 = min(wbase + 512       + 4 * lane, WIDTH - 4);
            const int n1 = min(wbase + 512 + 256 + 4 * lane, WIDTH - 4);
            p_r0 = *(const float4*)(xr_g + rowbase + n0);
            p_i0 = *(const float4*)(xi_g + rowbase + n0);
            p_r1 = *(const float4*)(xr_g + rowbase + n1);
            p_i1 = *(const float4*)(xi_g + rowbase + n1);
        }

        if (lane < 12) STAGE4(h_r, h_i, 128 + lane);

        // wave-private LDS: own writes complete -> readable, no block barrier
        asm volatile("s_waitcnt lgkmcnt(0)" ::: "memory");

        // ---- MFMA FIR + post-MLP epilogue, 2 tiles of 256 outputs ----
#pragma unroll
        for (int tt = 0; tt < 2; ++tt) {
            const int base_o = 256 * tt;
            const int i1 = base_o + 16 * jA + 8 * kg;          // B1 elements
            const half8 Bxr_h = *(const half8*)&s_rh[wv][i1];
            const half8 Bxi_h = *(const half8*)&s_ih[wv][i1];
            const half8 Bxr_l = *(const half8*)&s_rl[wv][i1];
            const half8 Bxi_l = *(const half8*)&s_il[wv][i1];
            const int i2 = base_o + 16 * jA + 32 + 8 * (kg & 1); // B2 mixed
            const _Float16* srcH = (kg < 2) ? s_rh[wv] : s_ih[wv];
            const _Float16* srcL = (kg < 2) ? s_rl[wv] : s_il[wv];
            const half8 Bmx_h = *(const half8*)&srcH[i2];
            const half8 Bmx_l = *(const half8*)&srcL[i2];

            floatx4 accr = {0.f, 0.f, 0.f, 0.f};
            floatx4 acci = {0.f, 0.f, 0.f, 0.f};
            accr = MFMA16(A1r_h,  Bxr_h, accr);  acci = MFMA16(A1i_h,  Bxr_h, acci);
            accr = MFMA16(A1mi_h, Bxi_h, accr);  acci = MFMA16(A1r_h,  Bxi_h, acci);
            accr = MFMA16(A2r_h,  Bmx_h, accr);  acci = MFMA16(A2i_h,  Bmx_h, acci);
            accr = MFMA16(A1r_h,  Bxr_l, accr);  acci = MFMA16(A1i_h,  Bxr_l, acci);
            accr = MFMA16(A1mi_h, Bxi_l, accr);  acci = MFMA16(A1r_h,  Bxi_l, acci);
            accr = MFMA16(A2r_h,  Bmx_l, accr);  acci = MFMA16(A2i_h,  Bmx_l, acci);
            accr = MFMA16(A1r_l,  Bxr_h, accr);  acci = MFMA16(A1i_l,  Bxr_h, acci);
            accr = MFMA16(A1mi_l, Bxi_h, accr);  acci = MFMA16(A1r_l,  Bxi_h, acci);
            accr = MFMA16(A2r_l,  Bmx_h, accr);  acci = MFMA16(A2i_l,  Bmx_h, acci);

            // epilogue: lane owns 4 CONSECUTIVE outputs obase..obase+3
            const int obase = wstart + base_o + 16 * jA + 4 * kg;
            float ox[8];
#pragma unroll
            for (int r = 0; r < 4; ++r) {
                const float zr  = accr[r], zi = acci[r];
                const float zsq = fmaf(zr, zr, zi * zi);
                const float rs  = (zsq > 0.f) ? __builtin_amdgcn_rsqf(zsq) : 0.f;
                const float zmag = zsq * rs;
                float zm = b2p;
#pragma unroll
                for (int f = 0; f < 8; ++f) {
                    const float gfv = fmaf(zmag, w1p[f], b1p[f]);
                    zm = fmaf(fmaxf(gfv, 0.f), w2p[f], zm);
                }
                const float t = SCALE_V * zm * rs;
                ox[2 * r]     = (zsq > 0.f) ? t * zr : SCALE_V * zm;
                ox[2 * r + 1] = t * zi;
            }
            float* po = &out[((long)brow * OUTW + obase) * 2];
            if (obase + 3 < OUTW) {
                if (row_aligned) {
                    *(float4*)(po)     = make_float4(ox[0], ox[1], ox[2], ox[3]);
                    *(float4*)(po + 4) = make_float4(ox[4], ox[5], ox[6], ox[7]);
                } else {
#pragma unroll
                    for (int r = 0; r < 4; ++r)
                        *(float2*)(po + 2 * r) = make_float2(ox[2 * r], ox[2 * r + 1]);
                }
            } else {
#pragma unroll
                for (int r = 0; r < 4; ++r)
                    if (obase + r < OUTW)
                        *(float2*)(po + 2 * r) = make_float2(ox[2 * r], ox[2 * r + 1]);
            }
        }
    }
#undef STAGE4
}

extern "C" void kernel_launch(void* const* d_in, const int* in_sizes, int n_in,
                              void* d_out, int out_size, void* d_ws, size_t ws_size,
                              hipStream_t stream) {
    float2* tbl = (float2*)d_ws;    // 8 KB of workspace
    fill_s_table<<<dim3((TBL_N + 255) / 256), 256, 0, stream>>>(
        (const float*)d_in[2], (const float*)d_in[3], tbl);

    dim3 grid(64, 16);              // 64 blocks/row x 16 rows; 4096 outputs/block
    fused_hammer_mfma<<<grid, 256, 0, stream>>>(
        (const float*)d_in[0], (const float*)d_in[1],
        (const float*)d_in[2], (const float*)d_in[3],
        (const float*)d_in[4], (const float*)d_in[5],
        (const float*)d_in[6], (const float*)d_in[7],
        (const float*)d_in[8], (const float*)d_in[9],
        tbl,
        (float*)d_out);
}